// Round 1
// baseline (1431.848 us; speedup 1.0000x reference)
//
#include <hip/hip_runtime.h>
#include <math.h>

// Problem constants (from reference): B=4, L=S=2048, H=16, E=D=64.
#define BB 4
#define LL 2048
#define HH 16
#define EE 64

constexpr int KBLK = 64;      // keys per LDS tile
constexpr int ROWS = 256;     // query rows per block == threads per block
constexpr float SCALE = 0.125f; // 1/sqrt(64)

// One thread owns one query row. q[] and o[] live in VGPRs (fully unrolled).
// K/V tiles staged in LDS; all lanes read the same K/V row element -> LDS
// broadcast (conflict-free). Online softmax in 16-key chunks.
__global__ __launch_bounds__(256, 2)
void attn_fwd_fp32(const float* __restrict__ Q, const float* __restrict__ K,
                   const float* __restrict__ V, float* __restrict__ O)
{
    const int bx  = blockIdx.x;
    const int nqt = LL / ROWS;                  // 8 q-tiles per (b,h)
    const int qt  = (nqt - 1) - (bx / (BB * HH)); // descending work order
    const int bh  = bx % (BB * HH);
    const int b   = bh / HH;
    const int h   = bh % HH;

    const int tid = threadIdx.x;
    const int row = qt * ROWS + tid;            // this thread's query row

    // [B,L,H,E] addressing: ((b*L + l)*H + h)*E + e ; H*E = 1024
    const size_t bh_base = (size_t)b * LL * HH * EE + (size_t)h * EE;
    const float* qrow = Q + bh_base + (size_t)row * (HH * EE);

    float q[EE];
    #pragma unroll
    for (int e4 = 0; e4 < EE / 4; ++e4) {
        float4 v = *(const float4*)(qrow + e4 * 4);
        q[e4*4+0] = v.x * SCALE;
        q[e4*4+1] = v.y * SCALE;
        q[e4*4+2] = v.z * SCALE;
        q[e4*4+3] = v.w * SCALE;
    }

    float o[EE];
    #pragma unroll
    for (int e = 0; e < EE; ++e) o[e] = 0.0f;
    float m = -INFINITY;
    float l = 0.0f;

    __shared__ float Ks[KBLK][EE];
    __shared__ float Vs[KBLK][EE];

    // rows in this block span [qt*256, qt*256+255]; max key index = row -> we
    // need tiles covering keys [0, (qt+1)*256) -> (qt+1)*4 tiles of 64.
    const int ntiles = (qt + 1) * (ROWS / KBLK);

    for (int t = 0; t < ntiles; ++t) {
        const int j0 = t * KBLK;

        __syncthreads();  // previous tile fully consumed
        // Cooperative load: 64 rows x 64 floats x 2 tensors = 32 KiB.
        // thread tid, step r: row jj = (tid>>4) + r*16, elems e = (tid&15)*4 .. +3
        #pragma unroll
        for (int r = 0; r < 4; ++r) {
            const int jj = (tid >> 4) + r * 16;
            const int e  = (tid & 15) * 4;
            const size_t gaddr = bh_base + (size_t)(j0 + jj) * (HH * EE) + e;
            *(float4*)(&Ks[jj][e]) = *(const float4*)(K + gaddr);
            *(float4*)(&Vs[jj][e]) = *(const float4*)(V + gaddr);
        }
        __syncthreads();

        // causal: valid keys have j0+jj <= row
        int jlim = row - j0;
        if (jlim >= 0) {
            if (jlim > KBLK - 1) jlim = KBLK - 1;

            #pragma unroll 1
            for (int c = 0; c < KBLK / 16; ++c) {
                const int jbase = c * 16;
                if (jbase <= jlim) {
                    float s[16];
                    #pragma unroll
                    for (int jj = 0; jj < 16; ++jj) {
                        const float4* krow = (const float4*)(&Ks[jbase + jj][0]);
                        float acc = 0.0f;
                        #pragma unroll
                        for (int e4 = 0; e4 < EE / 4; ++e4) {
                            float4 k4 = krow[e4];
                            acc += q[e4*4+0] * k4.x;
                            acc += q[e4*4+1] * k4.y;
                            acc += q[e4*4+2] * k4.z;
                            acc += q[e4*4+3] * k4.w;
                        }
                        s[jj] = acc;
                    }
                    // causal mask within chunk + chunk max
                    float cmax = -INFINITY;
                    #pragma unroll
                    for (int jj = 0; jj < 16; ++jj) {
                        if (jbase + jj > jlim) s[jj] = -INFINITY;
                        cmax = fmaxf(cmax, s[jj]);
                    }
                    // online softmax update
                    const float newm = fmaxf(m, cmax);
                    const float corr = __expf(m - newm); // m=-inf first time -> 0
                    l *= corr;
                    #pragma unroll
                    for (int e = 0; e < EE; ++e) o[e] *= corr;
                    #pragma unroll
                    for (int jj = 0; jj < 16; ++jj) {
                        const float p = __expf(s[jj] - newm); // masked -> exp(-inf)=0
                        l += p;
                        const float4* vrow = (const float4*)(&Vs[jbase + jj][0]);
                        #pragma unroll
                        for (int e4 = 0; e4 < EE / 4; ++e4) {
                            float4 v4 = vrow[e4];
                            o[e4*4+0] += p * v4.x;
                            o[e4*4+1] += p * v4.y;
                            o[e4*4+2] += p * v4.z;
                            o[e4*4+3] += p * v4.w;
                        }
                    }
                    m = newm;
                }
            }
        }
    }

    // epilogue: normalize and store [B,L,H,D]
    const float invl = 1.0f / l;
    float* orow = O + bh_base + (size_t)row * (HH * EE);
    #pragma unroll
    for (int e4 = 0; e4 < EE / 4; ++e4) {
        float4 v;
        v.x = o[e4*4+0] * invl;
        v.y = o[e4*4+1] * invl;
        v.z = o[e4*4+2] * invl;
        v.w = o[e4*4+3] * invl;
        *(float4*)(orow + e4 * 4) = v;
    }
}

extern "C" void kernel_launch(void* const* d_in, const int* in_sizes, int n_in,
                              void* d_out, int out_size, void* d_ws, size_t ws_size,
                              hipStream_t stream) {
    const float* Q = (const float*)d_in[0];
    const float* K = (const float*)d_in[1];
    const float* V = (const float*)d_in[2];
    float* Out = (float*)d_out;

    dim3 grid(BB * HH * (LL / ROWS)); // 4*16*8 = 512 blocks, high-work tiles first
    dim3 block(ROWS);
    hipLaunchKernelGGL(attn_fwd_fp32, grid, block, 0, stream, Q, K, V, Out);
}

// Round 4
// 244.811 us; speedup vs baseline: 5.8488x; 5.8488x over previous
//
#include <hip/hip_runtime.h>
#include <math.h>

// Problem constants: B=4, L=S=2048, H=16, E=D=64.
#define BB 4
#define LL 2048
#define HH 16
#define EE 64
#define HE (HH*EE)   // 1024 elements per (b,l) row

constexpr int QBLK  = 128;   // q rows per block (8 waves x 16 rows)
constexpr int KVBLK = 64;    // keys per LDS tile
constexpr int NW    = 8;     // waves per block
constexpr int NQT   = LL / QBLK;  // 16
constexpr int LDK   = 72;    // LDS row stride in shorts (64 + 8 pad)
constexpr float SCL2E = 0.18033688011112042f; // (1/sqrt(64)) * log2(e)

typedef short short8 __attribute__((ext_vector_type(8)));
typedef float f32x4  __attribute__((ext_vector_type(4)));

#define MFMA(a, b, c) __builtin_amdgcn_mfma_f32_16x16x32_bf16((a), (b), (c), 0, 0, 0)

static __device__ __forceinline__ unsigned short f2bf(float f) {
    unsigned u = __float_as_uint(f);
    return (unsigned short)((u + 0x7FFFu + ((u >> 16) & 1u)) >> 16);  // RNE
}
static __device__ __forceinline__ float bf2f(unsigned short s) {
    return __uint_as_float(((unsigned)s) << 16);
}

// Causal flash attention, bf16 MFMA with hi/lo-split QK^T (fp32-accurate scores).
__global__ __launch_bounds__(512, 4)
void attn_mfma(const float* __restrict__ Q, const float* __restrict__ K,
               const float* __restrict__ V, float* __restrict__ O)
{
    __shared__ short KsH[KVBLK * LDK];       // K hi bf16, [key][e], padded
    __shared__ short KsL[KVBLK * LDK];       // K lo bf16
    __shared__ short Vt [EE * LDK];          // V^T bf16, [d][key], XOR-swizzled cols
    __shared__ short Pl [NW * 16 * LDK];     // per-wave P, [q][key], padded

    const int bid = blockIdx.x;
    const int qt  = (NQT - 1) - (bid >> 6);       // descending work order
    const int bh  = bid & 63;
    const int b   = bh >> 4, h = bh & 15;
    const size_t base = (size_t)b * LL * HE + (size_t)h * EE;

    const int tid  = threadIdx.x;
    const int wave = tid >> 6, lane = tid & 63;
    const int g    = lane >> 4, c = lane & 15;    // quarter-wave group, col lane

    const int q0 = qt * QBLK + wave * 16;         // this wave's first q row

    // ---- Q fragments in registers: A-frag lane holds Q[q0 + c][ec*32 + 8g + i]
    short8 qh[2], ql[2];
    {
        const float* qp = Q + base + (size_t)(q0 + c) * HE + 8 * g;
        #pragma unroll
        for (int ec = 0; ec < 2; ++ec) {
            float4 f0 = *(const float4*)(qp + ec * 32);
            float4 f1 = *(const float4*)(qp + ec * 32 + 4);
            float fv[8] = {f0.x, f0.y, f0.z, f0.w, f1.x, f1.y, f1.z, f1.w};
            #pragma unroll
            for (int i = 0; i < 8; ++i) {
                float s = fv[i] * SCL2E;
                unsigned short hb = f2bf(s);
                float rem = s - bf2f(hb);
                qh[ec][i] = (short)hb;
                ql[ec][i] = (short)f2bf(rem);
            }
        }
    }

    f32x4 o[4];
    #pragma unroll
    for (int db = 0; db < 4; ++db)
        #pragma unroll
        for (int j = 0; j < 4; ++j) o[db][j] = 0.0f;
    float m_r[4] = {-INFINITY, -INFINITY, -INFINITY, -INFINITY};
    float l_r[4] = {0.f, 0.f, 0.f, 0.f};

    const int ntile = 2 * qt + 2;
    const int srow = tid >> 3;          // staging: key row 0..63
    const int scc  = (tid & 7) * 8;     // staging: 8-elem col chunk

    for (int t = 0; t < ntile; ++t) {
        const int j0 = t * KVBLK;

        __syncthreads();  // previous tile fully consumed
        // ---- stage K (hi/lo) and V^T (swizzled) : coalesced 32B global chunks
        {
            const float* kp = K + base + (size_t)(j0 + srow) * HE + scc;
            float4 a0 = *(const float4*)(kp);
            float4 a1 = *(const float4*)(kp + 4);
            float fv[8] = {a0.x, a0.y, a0.z, a0.w, a1.x, a1.y, a1.z, a1.w};
            short8 hv, lv;
            #pragma unroll
            for (int i = 0; i < 8; ++i) {
                unsigned short hb = f2bf(fv[i]);
                hv[i] = (short)hb;
                lv[i] = (short)f2bf(fv[i] - bf2f(hb));
            }
            *(short8*)(&KsH[srow * LDK + scc]) = hv;
            *(short8*)(&KsL[srow * LDK + scc]) = lv;

            const float* vp = V + base + (size_t)(j0 + srow) * HE + scc;
            float4 b0 = *(const float4*)(vp);
            float4 b1 = *(const float4*)(vp + 4);
            float gv[8] = {b0.x, b0.y, b0.z, b0.w, b1.x, b1.y, b1.z, b1.w};
            #pragma unroll
            for (int i = 0; i < 8; ++i) {
                const int d = scc + i;
                const int col = srow ^ (((d >> 3) & 7) << 3);  // XOR swizzle (8-elem gran)
                Vt[d * LDK + col] = (short)f2bf(gv[i]);
            }
        }
        __syncthreads();

        const int wq_end = q0 + 15;
        if (j0 <= wq_end) {                         // else: this wave fully masked
            // Mask needed unless the tile's LAST key <= the wave's FIRST row.
            // (Round-2 bug: compared against wq_end, letting rows q0..q0+14
            //  attend to future keys when j0+63 == q0+15.)
            const bool diag = (j0 + KVBLK - 1) > q0;

            // ---- QK^T (3-term split): S[16q x 64k], D-layout row=4g+r, col=c
            f32x4 s[4];
            #pragma unroll
            for (int kb = 0; kb < 4; ++kb) {
                f32x4 acc; acc[0]=0.f; acc[1]=0.f; acc[2]=0.f; acc[3]=0.f;
                #pragma unroll
                for (int ec = 0; ec < 2; ++ec) {
                    const int roff = (kb * 16 + c) * LDK + ec * 32 + 8 * g;
                    short8 kh = *(const short8*)(&KsH[roff]);
                    short8 kl = *(const short8*)(&KsL[roff]);
                    acc = MFMA(qh[ec], kh, acc);
                    acc = MFMA(ql[ec], kh, acc);
                    acc = MFMA(qh[ec], kl, acc);
                }
                s[kb] = acc;
            }

            // ---- mask + row max (reduce over 16 key-lanes)
            float tm[4];
            #pragma unroll
            for (int r = 0; r < 4; ++r) {
                if (diag) {
                    const int qrow = q0 + 4 * g + r;
                    #pragma unroll
                    for (int kb = 0; kb < 4; ++kb)
                        if (j0 + kb * 16 + c > qrow) s[kb][r] = -INFINITY;
                }
                tm[r] = fmaxf(fmaxf(s[0][r], s[1][r]), fmaxf(s[2][r], s[3][r]));
                #pragma unroll
                for (int xm = 1; xm <= 8; xm <<= 1)
                    tm[r] = fmaxf(tm[r], __shfl_xor(tm[r], xm));
            }

            // ---- online softmax update + P -> bf16 -> LDS
            #pragma unroll
            for (int r = 0; r < 4; ++r) {
                const float nm   = fmaxf(m_r[r], tm[r]);   // finite after tile 0
                const float corr = __builtin_amdgcn_exp2f(m_r[r] - nm); // -inf -> 0
                m_r[r] = nm;
                l_r[r] *= corr;
                #pragma unroll
                for (int db = 0; db < 4; ++db) o[db][r] *= corr;
                #pragma unroll
                for (int kb = 0; kb < 4; ++kb) {
                    const float p = __builtin_amdgcn_exp2f(s[kb][r] - nm);
                    const unsigned short pb = f2bf(p);
                    l_r[r] += bf2f(pb);   // denominator from the ROUNDED p
                    Pl[(wave * 16 + 4 * g + r) * LDK + kb * 16 + c] = (short)pb;
                }
            }

            // ---- PV: O[16q x 64d] += P * V   (A=P from LDS, B=V^T rows)
            #pragma unroll
            for (int kc = 0; kc < 2; ++kc) {
                short8 pa = *(const short8*)(&Pl[(wave * 16 + c) * LDK + kc * 32 + 8 * g]);
                #pragma unroll
                for (int db = 0; db < 4; ++db) {
                    const int d  = db * 16 + c;
                    const int k0 = (kc * 32 + 8 * g) ^ (((d >> 3) & 7) << 3);
                    short8 vb = *(const short8*)(&Vt[d * LDK + k0]);
                    o[db] = MFMA(pa, vb, o[db]);
                }
            }
        }
    }

    // ---- epilogue: reduce denominator across key-lanes, normalize, store
    #pragma unroll
    for (int r = 0; r < 4; ++r) {
        float ls = l_r[r];
        #pragma unroll
        for (int xm = 1; xm <= 8; xm <<= 1) ls += __shfl_xor(ls, xm);
        const float inv = 1.0f / ls;
        float* op = O + base + (size_t)(q0 + 4 * g + r) * HE + c;
        #pragma unroll
        for (int db = 0; db < 4; ++db)
            op[db * 16] = o[db][r] * inv;
    }
}

extern "C" void kernel_launch(void* const* d_in, const int* in_sizes, int n_in,
                              void* d_out, int out_size, void* d_ws, size_t ws_size,
                              hipStream_t stream) {
    const float* Q = (const float*)d_in[0];
    const float* K = (const float*)d_in[1];
    const float* V = (const float*)d_in[2];
    float* Out = (float*)d_out;

    dim3 grid(BB * HH * NQT);   // 1024 blocks, high-work q-tiles first
    dim3 block(512);
    hipLaunchKernelGGL(attn_mfma, grid, block, 0, stream, Q, K, V, Out);
}